// Round 4
// baseline (489.444 us; speedup 1.0000x reference)
//
#include <hip/hip_runtime.h>

typedef _Float16 half8 __attribute__((ext_vector_type(8)));
typedef _Float16 half4v __attribute__((ext_vector_type(4)));
typedef float floatx4 __attribute__((ext_vector_type(4)));

// ---------------------------------------------------------------------------
// Decoder: 6 conv_transpose3d (JAX SAME, no kernel flip), fp16 MFMA.
// R9: PERSISTENT MEGA-KERNEL, barrier v3. R8's residual ~30us/barrier was the
// single fan-out flag line: 1023 agent-scope (uncached) pollers serialize on
// one cacheline after the master's store. v3: per-block 64B-spaced flag lines
// (parallel independent reads), master broadcasts via 256 threads x 4 stores.
// Token scheme (0x5A170000+phase written into per-phase arrival/flag words)
// makes the barrier independent of initial memory contents -> no ctr memset
// dispatch needed despite harness ws re-poisoning. Arrivals packed 4B (16
// writers/line, proven cheap in R8). Phase bodies byte-identical to R8.
// ---------------------------------------------------------------------------

#define NBLK 1024u

__device__ __forceinline__ void gbar(unsigned* __restrict__ ctr, int phase) {
  // arrival[phase][b] = ctr[phase*1024 + b]            (packed 4B)
  // flag[phase][b]    = ctr[10240 + phase*16384 + b*16] (64B-spaced)
  unsigned* arr = ctr + phase * 1024;
  unsigned* flg = ctr + 10240 + phase * 16384;
  const unsigned tok = 0x5A170000u + (unsigned)phase;
  const int t = threadIdx.x;
  __syncthreads();  // all waves drained (vmcnt(0) per-wave before s_barrier)
  if (t == 0) {
    __builtin_amdgcn_fence(__ATOMIC_RELEASE, "agent");
    __hip_atomic_store(&arr[blockIdx.x], tok, __ATOMIC_RELAXED,
                       __HIP_MEMORY_SCOPE_AGENT);
  }
  if (blockIdx.x == 0) {
    if (t < 64) {
      const int base = t * 16;  // each lane owns 16 arrival words
      bool done = false;
      while (!done) {
        done = true;
#pragma unroll
        for (int i = 0; i < 16; i++) {
          if (__hip_atomic_load(&arr[base + i], __ATOMIC_RELAXED,
                                __HIP_MEMORY_SCOPE_AGENT) != tok)
            done = false;
        }
        if (!done) __builtin_amdgcn_s_sleep(2);
      }
      __builtin_amdgcn_fence(__ATOMIC_ACQUIRE, "agent");
    }
    __syncthreads();
    __builtin_amdgcn_fence(__ATOMIC_RELEASE, "agent");
    for (unsigned b = t; b < NBLK; b += 256u)
      __hip_atomic_store(&flg[b * 16], tok, __ATOMIC_RELAXED,
                         __HIP_MEMORY_SCOPE_AGENT);
    // fire-and-forget; block 0 proceeds (no anti-deps across phases)
  } else {
    if (t == 0) {
      while (__hip_atomic_load(&flg[blockIdx.x * 16], __ATOMIC_RELAXED,
                               __HIP_MEMORY_SCOPE_AGENT) != tok)
        __builtin_amdgcn_s_sleep(2);
      __builtin_amdgcn_fence(__ATOMIC_ACQUIRE, "agent");
    }
    __syncthreads();
  }
}

// Pad x (NCDHW fp32, 4^3 x 1024) -> P1 fp16 channels-last [5][5][5][1024].
__device__ __forceinline__ void pad_body(int vb, const float* __restrict__ X,
                                         _Float16* __restrict__ P) {
  int idx = vb * 256 + threadIdx.x;
  if (idx >= 125 * 1024) return;
  int c = idx & 1023;
  int r = idx >> 10;
  int px = r % 5, py = (r / 5) % 5, pz = r / 25;
  float v = 0.f;
  if (px >= 1 && py >= 1 && pz >= 1)
    v = X[c * 64 + (pz - 1) * 16 + (py - 1) * 4 + (px - 1)];
  P[idx] = (_Float16)v;
}

// Reduce partials -> ReLU -> fp16 -> padded next-layer input (borders = 0).
template <int POS, int COUT, int S2IN, int NSPL, int PS>
__device__ __forceinline__ void red_body(int vb, const float* __restrict__ Pp,
                                         _Float16* __restrict__ P) {
  constexpr int C4 = COUT / 4;
  constexpr size_t U3 =
      S2IN ? (size_t)(POS / 2) * (POS / 2) * (POS / 2) : (size_t)POS * POS * POS;
  int idx = vb * 256 + threadIdx.x;
  if (idx >= PS * PS * PS * C4) return;
  const int co = (idx % C4) * 4;
  const int r = idx / C4;
  const int px = r % PS, py = (r / PS) % PS, pz = r / (PS * PS);
  const int ix = px - 1, iy = py - 1, iz = pz - 1;
  float4 s = make_float4(0.f, 0.f, 0.f, 0.f);
  if ((unsigned)ix < (unsigned)POS && (unsigned)iy < (unsigned)POS &&
      (unsigned)iz < (unsigned)POS) {
    int j0, j1;
    size_t upos;
    if (S2IN) {
      const int pf[8] = {0, 8, 12, 16, 18, 22, 24, 26};
      const int tc[8] = {8, 4, 4, 2, 4, 2, 2, 1};
      const int cls = ((iz & 1) << 2) | ((iy & 1) << 1) | (ix & 1);
      j0 = pf[cls] * NSPL;
      j1 = j0 + tc[cls] * NSPL;
      constexpr int U = POS / 2;
      upos = ((size_t)(iz >> 1) * U + (iy >> 1)) * U + (ix >> 1);
    } else {
      j0 = 0;
      j1 = NSPL;
      upos = ((size_t)iz * POS + iy) * POS + ix;
    }
    const float* base = Pp + upos * COUT + co;
    for (int j = j0; j < j1; j++) {
      float4 v = *(const float4*)(base + (size_t)j * U3 * COUT);
      s.x += v.x; s.y += v.y; s.z += v.z; s.w += v.w;
    }
  }
  half4v h;
  h[0] = (_Float16)fmaxf(s.x, 0.f);
  h[1] = (_Float16)fmaxf(s.y, 0.f);
  h[2] = (_Float16)fmaxf(s.z, 0.f);
  h[3] = (_Float16)fmaxf(s.w, 0.f);
  *(half4v*)(P + (size_t)idx * 4) = h;
}

// MFMA implicit-GEMM conv body. Block = 256 threads = 4 waves. SMODE: 0 =
// stride1 tap-groups, 1 = stride2 (class,tap) pairs in bxi, 2 = stride2
// class-loop. STORE_MODE: 2 = fp16 ReLU store into padded (S+2)^3 buffer,
// 3 = fp32 partial slab store. LDS arena passed in (As [2][M][KP] then
// Bs [2][NTILE][KP]).
template <int CICHUNK, int CIN, int COUT, int NTILE, int TZ, int SOUTU,
          int PS, int SMODE, int TAPG, int STORE_MODE>
__device__ __forceinline__ void conv_body(
    int bxi, int byi, int bzi, const _Float16* __restrict__ P,
    const float* __restrict__ W, void* __restrict__ Optr, char* smem) {
  constexpr int M = TZ * 16;               // 64 or 128
  constexpr bool S2 = (SMODE != 0);
  constexpr int MTZ = SOUTU / TZ;
  constexpr int MTXY = SOUTU / 4;
  constexpr int MT3 = MTZ * MTXY * MTXY;
  constexpr int KB = 32;
  constexpr int KP = 40;
  constexpr int KBI = CICHUNK / KB;
  constexpr int NCI = CIN / CICHUNK;
  constexpr int S = S2 ? 2 * SOUTU : SOUTU;
  constexpr int WM = (M == 128) ? 4 : 2;   // waves along m
  constexpr int NSUB = (WM == 4) ? (NTILE / 16) : (NTILE / 32);
  constexpr int BJ = KB * NTILE / 256;     // B fp32 loads per thread
  constexpr size_t U3 = (size_t)SOUTU * SOUTU * SOUTU;

  _Float16* Asp = (_Float16*)smem;         // [2][M][KP]
  _Float16* Bsp = Asp + 2 * M * KP;        // [2][NTILE][KP]

  int bx = bxi;
  int cls = 0, tap0 = 0, cig = bzi, jspl = 0;
  int p_toz = 0, p_toy = 0, p_tox = 0, p_wtap = 0;
  if (SMODE == 0) {
    const int tg = cig / NCI;
    cig -= tg * NCI;
    tap0 = tg * TAPG;
    jspl = bzi;                            // tg*NCI + cig
  } else if (SMODE == 1) {
    const int p = bx / MT3;
    bx -= p * MT3;
    jspl = p * NCI + cig;
    cls = (p >= 8) + (p >= 12) + (p >= 16) + (p >= 18) + (p >= 22) +
          (p >= 24) + (p >= 26);
    const int pf = cls == 0 ? 0 : cls == 1 ? 8 : cls == 2 ? 12
                 : cls == 3 ? 16 : cls == 4 ? 18 : cls == 5 ? 22
                 : cls == 6 ? 24 : 26;
    const int tl = p - pf;
    const int lz = (cls >> 2) & 1, ly = (cls >> 1) & 1, lx = cls & 1;
    const int shx = lx ? 0 : 1, shy = ly ? 0 : 1;
    const int iz = tl >> (shx + shy);
    const int rem = tl & ((1 << (shx + shy)) - 1);
    const int iy = rem >> shx;
    const int ix = rem & ((1 << shx) - 1);
    p_toz = lz ? 1 : iz;
    p_toy = ly ? 1 : iy;
    p_tox = lx ? 1 : ix;
    const int wz = lz ? 1 : 2 * iz, wy = ly ? 1 : 2 * iy,
              wx = lx ? 1 : 2 * ix;
    p_wtap = (wz * 3 + wy) * 3 + wx;
  } else {
    cls = bx / MT3;
    bx -= cls * MT3;
  }
  const int clz = (cls >> 2) & 1, cly = (cls >> 1) & 1, clx = cls & 1;

  const int u0z = (bx / (MTXY * MTXY)) * TZ;
  const int u0y = ((bx / MTXY) % MTXY) * 4;
  const int u0x = (bx % MTXY) * 4;
  const int n_base = byi * NTILE;

  const int t = threadIdx.x;
  const int lane = t & 63;
  const int wave = t >> 6;

  // A staging: thread t -> position sp (4x4x4 z-major), k-chunk skq
  const int skq = t & 3;
  const int sp = t >> 2;
  const int spx = sp & 3, spy = (sp >> 2) & 3, spz = sp >> 4;
  // B staging: thread t -> n-row nB, k range [k0B, k0B+BJ)
  const int nB = t & (NTILE - 1);
  const int k0B = (t / NTILE) * BJ;
  // compute mapping
  const int m0w = (WM == 4) ? wave * 32 : (wave >> 1) * 32;
  const int n0w = (WM == 4) ? 0 : (wave & 1) * 32;
  const int fr = lane & 15;
  const int fq = lane >> 4;

  const int cz = S2 ? (clz ? 1 : 2) : 3;
  const int cy = S2 ? (cly ? 1 : 2) : 3;
  const int cx = S2 ? (clx ? 1 : 2) : 3;
  const int shx2 = clx ? 0 : 1, shy2 = cly ? 0 : 1;

  int NIT;
  if (SMODE == 0) NIT = TAPG * KBI;
  else if (SMODE == 1) NIT = KBI;
  else NIT = cz * cy * cx * KBI;

  floatx4 acc[2][NSUB];
#pragma unroll
  for (int i = 0; i < 2; i++)
#pragma unroll
    for (int s = 0; s < NSUB; s++) acc[i][s] = {0.f, 0.f, 0.f, 0.f};

  half8 rA0 = {}, rA1 = {}, nA0 = {}, nA1 = {};
  float rB[BJ] = {}, nBv[BJ] = {};

  auto load_it = [&](int it, half8& A0, half8& A1, float* BW) {
    int tap, kb;
    if (SMODE == 1) { tap = 0; kb = it; }
    else if (KBI == 1) { tap = it; kb = 0; }
    else { tap = it / KBI; kb = it - tap * KBI; }
    int toz, toy, tox, wtap;
    if (SMODE == 1) {
      toz = p_toz; toy = p_toy; tox = p_tox; wtap = p_wtap;
    } else if (SMODE == 0) {
      const int tt = tap0 + tap;
      const int iz = tt / 9;
      const int rem = tt - iz * 9;
      const int iy = rem / 3;
      const int ix = rem - iy * 3;
      toz = iz; toy = iy; tox = ix;
      wtap = tt;
    } else {
      const int iz = tap >> (shx2 + shy2);
      const int rem = tap & ((1 << (shx2 + shy2)) - 1);
      const int iy = rem >> shx2;
      const int ix = rem & ((1 << shx2) - 1);
      toz = clz ? 1 : iz; toy = cly ? 1 : iy; tox = clx ? 1 : ix;
      const int wz = clz ? 1 : 2 * iz, wy = cly ? 1 : 2 * iy,
                wx = clx ? 1 : 2 * ix;
      wtap = (wz * 3 + wy) * 3 + wx;
    }
    const int kof0 = cig * CICHUNK + kb * KB;
    const size_t pb =
        ((size_t)(((u0z + toz + spz) * PS + (u0y + toy + spy)) * PS +
                  (u0x + tox + spx))) * CIN + kof0 + skq * 8;
    A0 = *(const half8*)(P + pb);
    if (M == 128)
      A1 = *(const half8*)(P + pb + (size_t)4 * PS * PS * CIN);
    const float* wb =
        W + ((size_t)wtap * CIN + kof0 + k0B) * COUT + n_base + nB;
#pragma unroll
    for (int j = 0; j < BJ; j++) BW[j] = wb[(size_t)j * COUT];
  };

  auto stage = [&](int buf, half8& A0, half8& A1, float* BW) {
    *(half8*)&Asp[((size_t)buf * M + sp) * KP + skq * 8] = A0;
    if (M == 128)
      *(half8*)&Asp[((size_t)buf * M + sp + 64) * KP + skq * 8] = A1;
    if (BJ == 8) {
      half8 hb;
#pragma unroll
      for (int j = 0; j < 8; j++) hb[j] = (_Float16)BW[j];
      *(half8*)&Bsp[((size_t)buf * NTILE + nB) * KP + k0B] = hb;
    } else {
      half4v hb;
#pragma unroll
      for (int j = 0; j < 4; j++) hb[j] = (_Float16)BW[j];
      *(half4v*)&Bsp[((size_t)buf * NTILE + nB) * KP + k0B] = hb;
    }
  };

  load_it(0, rA0, rA1, rB);
  stage(0, rA0, rA1, rB);
  __syncthreads();

  int cur = 0;
  for (int it = 0; it < NIT; ++it) {
    const bool more = (it + 1 < NIT);
    if (more) load_it(it + 1, nA0, nA1, nBv);
    half8 a0 = *(const half8*)&Asp[((size_t)cur * M + m0w + fr) * KP + fq * 8];
    half8 a1 =
        *(const half8*)&Asp[((size_t)cur * M + m0w + 16 + fr) * KP + fq * 8];
#pragma unroll
    for (int s = 0; s < NSUB; s++) {
      half8 b = *(const half8*)&Bsp[((size_t)cur * NTILE + n0w + s * 16 + fr) *
                                        KP + fq * 8];
      acc[0][s] = __builtin_amdgcn_mfma_f32_16x16x32_f16(a0, b, acc[0][s], 0, 0, 0);
      acc[1][s] = __builtin_amdgcn_mfma_f32_16x16x32_f16(a1, b, acc[1][s], 0, 0, 0);
    }
    if (more) {
      stage(cur ^ 1, nA0, nA1, nBv);
      __syncthreads();
    }
    cur ^= 1;
  }

#pragma unroll
  for (int i = 0; i < 2; i++) {
#pragma unroll
    for (int r = 0; r < 4; r++) {
      const int m = m0w + i * 16 + fq * 4 + r;
      const int mz = m >> 4, my = (m >> 2) & 3, mx = m & 3;
      if (STORE_MODE == 2) {
        const int oz = 2 * (u0z + mz) + clz;
        const int oy = 2 * (u0y + my) + cly;
        const int ox = 2 * (u0x + mx) + clx;
        _Float16* o = (_Float16*)Optr +
            ((size_t)(((oz + 1) * (S + 2) + (oy + 1)) * (S + 2) + (ox + 1))) *
                COUT + n_base + n0w;
#pragma unroll
        for (int s = 0; s < NSUB; s++)
          o[s * 16 + fr] = (_Float16)fmaxf(acc[i][s][r], 0.f);
      } else {
        const size_t pos =
            ((size_t)((u0z + mz) * SOUTU + (u0y + my))) * SOUTU + (u0x + mx);
        float* o = (float*)Optr + ((size_t)jspl * U3 + pos) * COUT + n_base +
                   n0w;
#pragma unroll
        for (int s = 0; s < NSUB; s++) o[s * 16 + fr] = acc[i][s][r];
      }
    }
  }
}

// Layer 6: 32 -> 1 channels, per-output dot product from padded fp16 P6.
__device__ __forceinline__ void conv6_body(int vb,
                                           const _Float16* __restrict__ P,
                                           const float* __restrict__ W6,
                                           float* __restrict__ O, char* smem) {
  float* w = (float*)smem;  // 864 floats
  for (int i = threadIdx.x; i < 864; i += 256) w[i] = W6[i];
  __syncthreads();
  int idx = vb * 256 + threadIdx.x;  // 32768 outputs
  int x = idx & 31, y = (idx >> 5) & 31, z = idx >> 10;
  float a = 0.f;
  for (int dz = 0; dz < 3; dz++)
    for (int dy = 0; dy < 3; dy++)
      for (int dx = 0; dx < 3; dx++) {
        const _Float16* p =
            P + (size_t)(((z + dz) * 34 + (y + dy)) * 34 + (x + dx)) * 32;
        const float* ww = &w[((dz * 3 + dy) * 3 + dx) * 32];
#pragma unroll
        for (int c = 0; c < 32; c += 8) {
          half8 pv = *(const half8*)&p[c];
#pragma unroll
          for (int u = 0; u < 8; u++) a += (float)pv[u] * ww[c + u];
        }
      }
  O[idx] = a;
}

__global__ __launch_bounds__(256, 4) void mega_k(
    const float* __restrict__ x, const float* __restrict__ w1,
    const float* __restrict__ w2, const float* __restrict__ w3,
    const float* __restrict__ w4, const float* __restrict__ w5,
    const float* __restrict__ w6, float* __restrict__ out,
    float* __restrict__ Q1, float* __restrict__ Q2, float* __restrict__ Q3,
    float* __restrict__ Q4, _Float16* __restrict__ P1,
    _Float16* __restrict__ P2, _Float16* __restrict__ P3,
    _Float16* __restrict__ P4, _Float16* __restrict__ P5,
    _Float16* __restrict__ P6, unsigned* __restrict__ ctr) {
  __shared__ __align__(16) char smem[30720];  // max: As 2*128*40*2 + Bs 2*64*40*2
  const int b0 = blockIdx.x;
  const int gstep = gridDim.x;

  // phase 0: pad x -> P1 (500 vb) + zero P6 (615 vb, 157216 half8s)
  for (int vb = b0; vb < 1115; vb += gstep) {
    if (vb < 500) {
      pad_body(vb, x, P1);
    } else {
      int i = (vb - 500) * 256 + threadIdx.x;
      if (i < 157216) ((half8*)P6)[i] = half8{};
    }
  }
  gbar(ctr, 0);

  // phase 1: conv1 1024->512, 4^3 -> 8^3, s2 pairs; grid(27,8,4) = 864
  for (int vb = b0; vb < 864; vb += gstep)
    conv_body<256, 1024, 512, 64, 4, 4, 5, 1, 0, 3>(
        vb % 27, (vb / 27) % 8, vb / 216, P1, w1, Q1, smem);
  gbar(ctr, 1);

  // phase 2: red1 -> P2; 500 vb
  for (int vb = b0; vb < 500; vb += gstep) red_body<8, 512, 1, 4, 10>(vb, Q1, P2);
  gbar(ctr, 2);

  // phase 3: conv2 512->256, 8^3, s1; grid(4,4,24) = 384
  for (int vb = b0; vb < 384; vb += gstep)
    conv_body<64, 512, 256, 64, 8, 8, 10, 0, 9, 3>(
        vb % 4, (vb / 4) % 4, vb / 16, P2, w2, Q2, smem);
  gbar(ctr, 3);

  // phase 4: red2 -> P3; 183 vb
  for (int vb = b0; vb < 183; vb += gstep) red_body<8, 256, 0, 24, 9>(vb, Q2, P3);
  gbar(ctr, 4);

  // phase 5: conv3 256->128, 8^3 -> 16^3, s2 pairs; grid(108,2,2) = 432
  for (int vb = b0; vb < 432; vb += gstep)
    conv_body<128, 256, 128, 64, 8, 8, 9, 1, 0, 3>(
        vb % 108, (vb / 108) % 2, vb / 216, P3, w3, Q3, smem);
  gbar(ctr, 5);

  // phase 6: red3 -> P4; 729 vb
  for (int vb = b0; vb < 729; vb += gstep)
    red_body<16, 128, 1, 2, 18>(vb, Q3, P4);
  gbar(ctr, 6);

  // phase 7: conv4 128->64, 16^3, s1; grid(32,1,12) = 384
  for (int vb = b0; vb < 384; vb += gstep)
    conv_body<32, 128, 64, 64, 8, 16, 18, 0, 9, 3>(
        vb % 32, 0, vb / 32, P4, w4, Q4, smem);
  gbar(ctr, 7);

  // phase 8: red4 -> P5; 308 vb
  for (int vb = b0; vb < 308; vb += gstep)
    red_body<16, 64, 0, 12, 17>(vb, Q4, P5);
  gbar(ctr, 8);

  // phase 9: conv5 64->32, 16^3 -> 32^3, s2 class-loop, fp16 ReLU -> P6; 256 vb
  for (int vb = b0; vb < 256; vb += gstep)
    conv_body<64, 64, 32, 32, 8, 16, 17, 2, 0, 2>(vb, 0, 0, P5, w5, P6, smem);
  gbar(ctr, 9);

  // phase 10: conv6 32->1, 32^3; 128 vb
  for (int vb = b0; vb < 128; vb += gstep) conv6_body(vb, P6, w6, out, smem);
}

extern "C" void kernel_launch(void* const* d_in, const int* in_sizes, int n_in,
                              void* d_out, int out_size, void* d_ws,
                              size_t ws_size, hipStream_t stream) {
  const float* x  = (const float*)d_in[0];
  const float* w1 = (const float*)d_in[1];
  const float* w2 = (const float*)d_in[2];
  const float* w3 = (const float*)d_in[3];
  const float* w4 = (const float*)d_in[4];
  const float* w5 = (const float*)d_in[5];
  const float* w6 = (const float*)d_in[6];
  float* out = (float*)d_out;

  // barrier state: arrival[10][1024] (4B packed) + flag[10][1024] (64B lines)
  // = 10240 + 163840 uints = 680KB. Token scheme -> no memset needed.
  unsigned* ctr = (unsigned*)d_ws;
  // fp32 partial slabs (start at +174080 uints = 696320B, 16B aligned)
  float* Q1 = (float*)d_ws + 174080;         // 108 * 64   * 512 = 3538944
  float* Q2 = Q1 + 3538944;                  // 24  * 512  * 256 = 3145728
  float* Q3 = Q2 + 3145728;                  // 54  * 512  * 128 = 3538944
  float* Q4 = Q3 + 3538944;                  // 12  * 4096 * 64  = 3145728
  // fp16 padded activations
  _Float16* P1 = (_Float16*)(Q4 + 3145728);  // 5^3  * 1024 = 128000
  _Float16* P2 = P1 + 128000;                // 10^3 * 512  = 512000
  _Float16* P3 = P2 + 512000;                // 9^3  * 256  = 186624
  _Float16* P4 = P3 + 186624;                // 18^3 * 128  = 746496
  _Float16* P5 = P4 + 746496;                // 17^3 * 64   = 314432
  _Float16* P6 = P5 + 314432;                // 34^3 * 32   = 1257728

  mega_k<<<NBLK, 256, 0, stream>>>(x, w1, w2, w3, w4, w5, w6, out, Q1, Q2, Q3,
                                   Q4, P1, P2, P3, P4, P5, P6, ctr);

  (void)in_sizes; (void)n_in; (void)out_size; (void)ws_size;
}

// Round 5
// 207.770 us; speedup vs baseline: 2.3557x; 2.3557x over previous
//
#include <hip/hip_runtime.h>

typedef _Float16 half8 __attribute__((ext_vector_type(8)));
typedef _Float16 half4v __attribute__((ext_vector_type(4)));
typedef float floatx4 __attribute__((ext_vector_type(4)));

// ---------------------------------------------------------------------------
// Decoder: 6 conv_transpose3d (JAX SAME, no kernel flip), fp16 MFMA.
// R10: REVERT to R5 multi-dispatch structure (persistent-kernel arc R7-R9
// abandoned: grid barriers cost ~30us each regardless of implementation,
// vs ~small dispatch-boundary cost). R5 bodies verbatim. Deltas vs R5:
// (1) P6 memset folded into red4z_k (blocks >= 308 zero P6) -> one fewer
// dispatch; (2) conv6 at 256 blocks x 128 threads (1 block/CU).
// ---------------------------------------------------------------------------

__global__ __launch_bounds__(256) void pad_x_k(const float* __restrict__ X,
                                               _Float16* __restrict__ P) {
  int idx = blockIdx.x * 256 + threadIdx.x;   // P1: [5][5][5][1024]
  if (idx >= 125 * 1024) return;
  int c = idx & 1023;
  int r = idx >> 10;
  int px = r % 5, py = (r / 5) % 5, pz = r / 25;
  float v = 0.f;
  if (px >= 1 && py >= 1 && pz >= 1)
    v = X[c * 64 + (pz - 1) * 16 + (py - 1) * 4 + (px - 1)];  // NCDHW -> cl
  P[idx] = (_Float16)v;
}

// Reduce partials -> ReLU -> fp16 -> padded next-layer input (borders = 0).
// POS = producer spatial size, S2IN = producer was stride-2 (class-variable
// split count), NSPL = ci-splits (s2) or total splits (s1), PS = padded size.
template <int POS, int COUT, int S2IN, int NSPL, int PS>
__device__ __forceinline__ void red_body(int vb, const float* __restrict__ Pp,
                                         _Float16* __restrict__ P) {
  constexpr int C4 = COUT / 4;
  constexpr size_t U3 =
      S2IN ? (size_t)(POS / 2) * (POS / 2) * (POS / 2) : (size_t)POS * POS * POS;
  int idx = vb * 256 + threadIdx.x;
  if (idx >= PS * PS * PS * C4) return;
  const int co = (idx % C4) * 4;
  const int r = idx / C4;
  const int px = r % PS, py = (r / PS) % PS, pz = r / (PS * PS);
  const int ix = px - 1, iy = py - 1, iz = pz - 1;
  float4 s = make_float4(0.f, 0.f, 0.f, 0.f);
  if ((unsigned)ix < (unsigned)POS && (unsigned)iy < (unsigned)POS &&
      (unsigned)iz < (unsigned)POS) {
    int j0, j1;
    size_t upos;
    if (S2IN) {
      const int pf[8] = {0, 8, 12, 16, 18, 22, 24, 26};
      const int tc[8] = {8, 4, 4, 2, 4, 2, 2, 1};
      const int cls = ((iz & 1) << 2) | ((iy & 1) << 1) | (ix & 1);
      j0 = pf[cls] * NSPL;
      j1 = j0 + tc[cls] * NSPL;
      constexpr int U = POS / 2;
      upos = ((size_t)(iz >> 1) * U + (iy >> 1)) * U + (ix >> 1);
    } else {
      j0 = 0;
      j1 = NSPL;
      upos = ((size_t)iz * POS + iy) * POS + ix;
    }
    const float* base = Pp + upos * COUT + co;
    for (int j = j0; j < j1; j++) {
      float4 v = *(const float4*)(base + (size_t)j * U3 * COUT);
      s.x += v.x; s.y += v.y; s.z += v.z; s.w += v.w;
    }
  }
  half4v h;
  h[0] = (_Float16)fmaxf(s.x, 0.f);
  h[1] = (_Float16)fmaxf(s.y, 0.f);
  h[2] = (_Float16)fmaxf(s.z, 0.f);
  h[3] = (_Float16)fmaxf(s.w, 0.f);
  *(half4v*)(P + (size_t)idx * 4) = h;
}

template <int POS, int COUT, int S2IN, int NSPL, int PS>
__global__ __launch_bounds__(256) void red_k(const float* __restrict__ Pp,
                                             _Float16* __restrict__ P) {
  red_body<POS, COUT, S2IN, NSPL, PS>(blockIdx.x, Pp, P);
}

// red4 + P6 zero fused: blocks < 308 do red4 (Q4 -> P5); blocks >= 308 zero
// P6 (615 blocks cover 157216 half8s = 34^3*32 halfs). Saves the memset
// dispatch; conv5 (next dispatch) then writes P6's interior over the zeros.
__global__ __launch_bounds__(256) void red4z_k(const float* __restrict__ Q4,
                                               _Float16* __restrict__ P5,
                                               _Float16* __restrict__ P6) {
  if (blockIdx.x < 308) {
    red_body<16, 64, 0, 12, 17>(blockIdx.x, Q4, P5);
  } else {
    int i = (blockIdx.x - 308) * 256 + threadIdx.x;
    if (i < 157216) ((half8*)P6)[i] = half8{};
  }
}

// MFMA implicit-GEMM conv. Block = 256 threads = 4 waves. Input: fp16 padded
// channels-last, PS per dim (left-pad 1; s1 layers additionally have right
// pad). SMODE: 0 = stride1 tap-groups, 1 = stride2 (class,tap) pairs in
// blockIdx.x, 2 = stride2 class-loop. STORE_MODE: 2 = fp16 ReLU store into
// padded (S+2)^3 buffer, 3 = fp32 partial slab store (no atomics).
template <int CICHUNK, int CIN, int COUT, int NTILE, int TZ, int SOUTU,
          int PS, int SMODE, int TAPG, int STORE_MODE>
__global__ __launch_bounds__(256) void conv_mfma_k(
    const _Float16* __restrict__ P, const float* __restrict__ W,
    void* __restrict__ Optr) {
  constexpr int M = TZ * 16;               // 64 or 128
  constexpr bool S2 = (SMODE != 0);
  constexpr int MTZ = SOUTU / TZ;
  constexpr int MTXY = SOUTU / 4;
  constexpr int MT3 = MTZ * MTXY * MTXY;
  constexpr int KB = 32;
  constexpr int KP = 40;
  constexpr int KBI = CICHUNK / KB;
  constexpr int NCI = CIN / CICHUNK;
  constexpr int S = S2 ? 2 * SOUTU : SOUTU;
  constexpr int WM = (M == 128) ? 4 : 2;   // waves along m
  constexpr int NSUB = (WM == 4) ? (NTILE / 16) : (NTILE / 32);
  constexpr int BJ = KB * NTILE / 256;     // B fp32 loads per thread
  constexpr size_t U3 = (size_t)SOUTU * SOUTU * SOUTU;

  __shared__ __align__(16) _Float16 As[M][KP];
  __shared__ __align__(16) _Float16 Bs[NTILE][KP];

  int bx = blockIdx.x;
  int cls = 0, tap0 = 0, cig = blockIdx.z, jspl = 0;
  int p_toz = 0, p_toy = 0, p_tox = 0, p_wtap = 0;
  if (SMODE == 0) {
    const int tg = cig / NCI;
    cig -= tg * NCI;
    tap0 = tg * TAPG;
    jspl = blockIdx.z;                     // tg*NCI + cig
  } else if (SMODE == 1) {
    const int p = bx / MT3;
    bx -= p * MT3;
    jspl = p * NCI + cig;
    cls = (p >= 8) + (p >= 12) + (p >= 16) + (p >= 18) + (p >= 22) +
          (p >= 24) + (p >= 26);
    const int pf = cls == 0 ? 0 : cls == 1 ? 8 : cls == 2 ? 12
                 : cls == 3 ? 16 : cls == 4 ? 18 : cls == 5 ? 22
                 : cls == 6 ? 24 : 26;
    const int tl = p - pf;
    const int lz = (cls >> 2) & 1, ly = (cls >> 1) & 1, lx = cls & 1;
    const int shx = lx ? 0 : 1, shy = ly ? 0 : 1;
    const int iz = tl >> (shx + shy);
    const int rem = tl & ((1 << (shx + shy)) - 1);
    const int iy = rem >> shx;
    const int ix = rem & ((1 << shx) - 1);
    p_toz = lz ? 1 : iz;
    p_toy = ly ? 1 : iy;
    p_tox = lx ? 1 : ix;
    const int wz = lz ? 1 : 2 * iz, wy = ly ? 1 : 2 * iy,
              wx = lx ? 1 : 2 * ix;
    p_wtap = (wz * 3 + wy) * 3 + wx;
  } else {
    cls = bx / MT3;
    bx -= cls * MT3;
  }
  const int clz = (cls >> 2) & 1, cly = (cls >> 1) & 1, clx = cls & 1;

  const int u0z = (bx / (MTXY * MTXY)) * TZ;
  const int u0y = ((bx / MTXY) % MTXY) * 4;
  const int u0x = (bx % MTXY) * 4;
  const int n_base = blockIdx.y * NTILE;

  const int t = threadIdx.x;
  const int lane = t & 63;
  const int wave = t >> 6;

  // A staging: thread t -> position sp (4x4x4 z-major), k-chunk skq
  const int skq = t & 3;
  const int sp = t >> 2;
  const int spx = sp & 3, spy = (sp >> 2) & 3, spz = sp >> 4;
  // B staging: thread t -> n-row nB, k range [k0B, k0B+BJ)
  const int nB = t & (NTILE - 1);
  const int k0B = (t / NTILE) * BJ;
  // compute mapping
  const int m0w = (WM == 4) ? wave * 32 : (wave >> 1) * 32;
  const int n0w = (WM == 4) ? 0 : (wave & 1) * 32;
  const int fr = lane & 15;
  const int fq = lane >> 4;

  const int cz = S2 ? (clz ? 1 : 2) : 3;
  const int cy = S2 ? (cly ? 1 : 2) : 3;
  const int cx = S2 ? (clx ? 1 : 2) : 3;
  const int shx2 = clx ? 0 : 1, shy2 = cly ? 0 : 1;

  int NIT;
  if (SMODE == 0) NIT = TAPG * KBI;
  else if (SMODE == 1) NIT = KBI;
  else NIT = cz * cy * cx * KBI;

  floatx4 acc[2][NSUB];
#pragma unroll
  for (int i = 0; i < 2; i++)
#pragma unroll
    for (int s = 0; s < NSUB; s++) acc[i][s] = {0.f, 0.f, 0.f, 0.f};

  half8 rA0 = {}, rA1 = {}, nA0 = {}, nA1 = {};
  float rB[BJ] = {}, nBv[BJ] = {};

  auto load_it = [&](int it, half8& A0, half8& A1, float* BW) {
    int tap, kb;
    if (SMODE == 1) { tap = 0; kb = it; }
    else if (KBI == 1) { tap = it; kb = 0; }
    else { tap = it / KBI; kb = it - tap * KBI; }
    int toz, toy, tox, wtap;
    if (SMODE == 1) {
      toz = p_toz; toy = p_toy; tox = p_tox; wtap = p_wtap;
    } else if (SMODE == 0) {
      const int tt = tap0 + tap;
      const int iz = tt / 9;
      const int rem = tt - iz * 9;
      const int iy = rem / 3;
      const int ix = rem - iy * 3;
      toz = iz; toy = iy; tox = ix;
      wtap = tt;
    } else {
      const int iz = tap >> (shx2 + shy2);
      const int rem = tap & ((1 << (shx2 + shy2)) - 1);
      const int iy = rem >> shx2;
      const int ix = rem & ((1 << shx2) - 1);
      toz = clz ? 1 : iz; toy = cly ? 1 : iy; tox = clx ? 1 : ix;
      const int wz = clz ? 1 : 2 * iz, wy = cly ? 1 : 2 * iy,
                wx = clx ? 1 : 2 * ix;
      wtap = (wz * 3 + wy) * 3 + wx;
    }
    const int kof0 = cig * CICHUNK + kb * KB;
    const size_t pb =
        ((size_t)(((u0z + toz + spz) * PS + (u0y + toy + spy)) * PS +
                  (u0x + tox + spx))) * CIN + kof0 + skq * 8;
    A0 = *(const half8*)(P + pb);
    if (M == 128)
      A1 = *(const half8*)(P + pb + (size_t)4 * PS * PS * CIN);
    const float* wb =
        W + ((size_t)wtap * CIN + kof0 + k0B) * COUT + n_base + nB;
#pragma unroll
    for (int j = 0; j < BJ; j++) BW[j] = wb[(size_t)j * COUT];
  };

  load_it(0, rA0, rA1, rB);

  for (int it = 0; it < NIT; ++it) {
    *(half8*)&As[sp][skq * 8] = rA0;
    if (M == 128) *(half8*)&As[sp + 64][skq * 8] = rA1;
    if (BJ == 8) {
      half8 hb;
#pragma unroll
      for (int j = 0; j < 8; j++) hb[j] = (_Float16)rB[j];
      *(half8*)&Bs[nB][k0B] = hb;
    } else {
      half4v hb;
#pragma unroll
      for (int j = 0; j < 4; j++) hb[j] = (_Float16)rB[j];
      *(half4v*)&Bs[nB][k0B] = hb;
    }
    __syncthreads();
    if (it + 1 < NIT) load_it(it + 1, nA0, nA1, nBv);
    half8 a0 = *(const half8*)&As[m0w + fr][fq * 8];
    half8 a1 = *(const half8*)&As[m0w + 16 + fr][fq * 8];
#pragma unroll
    for (int s = 0; s < NSUB; s++) {
      half8 b = *(const half8*)&Bs[n0w + s * 16 + fr][fq * 8];
      acc[0][s] = __builtin_amdgcn_mfma_f32_16x16x32_f16(a0, b, acc[0][s], 0, 0, 0);
      acc[1][s] = __builtin_amdgcn_mfma_f32_16x16x32_f16(a1, b, acc[1][s], 0, 0, 0);
    }
    __syncthreads();
    rA0 = nA0;
    rA1 = nA1;
#pragma unroll
    for (int j = 0; j < BJ; j++) rB[j] = nBv[j];
  }

#pragma unroll
  for (int i = 0; i < 2; i++) {
#pragma unroll
    for (int r = 0; r < 4; r++) {
      const int m = m0w + i * 16 + fq * 4 + r;
      const int mz = m >> 4, my = (m >> 2) & 3, mx = m & 3;
      if (STORE_MODE == 2) {
        const int oz = 2 * (u0z + mz) + clz;
        const int oy = 2 * (u0y + my) + cly;
        const int ox = 2 * (u0x + mx) + clx;
        _Float16* o = (_Float16*)Optr +
            ((size_t)(((oz + 1) * (S + 2) + (oy + 1)) * (S + 2) + (ox + 1))) *
                COUT + n_base + n0w;
#pragma unroll
        for (int s = 0; s < NSUB; s++)
          o[s * 16 + fr] = (_Float16)fmaxf(acc[i][s][r], 0.f);
      } else {
        const size_t pos =
            ((size_t)((u0z + mz) * SOUTU + (u0y + my))) * SOUTU + (u0x + mx);
        float* o = (float*)Optr + ((size_t)jspl * U3 + pos) * COUT + n_base +
                   n0w;
#pragma unroll
        for (int s = 0; s < NSUB; s++) o[s * 16 + fr] = acc[i][s][r];
      }
    }
  }
}

// Layer 6: 32 -> 1 channels, per-output dot product from padded fp16 P6.
// 256 blocks x 128 threads -> 1 block per CU.
__global__ __launch_bounds__(128) void conv6_k(const _Float16* __restrict__ P,
                                               const float* __restrict__ W6,
                                               float* __restrict__ O) {
  __shared__ __align__(16) float w[864];  // 27*32
  for (int i = threadIdx.x; i < 864; i += 128) w[i] = W6[i];
  __syncthreads();
  int idx = blockIdx.x * 128 + threadIdx.x;  // 32768 outputs
  int x = idx & 31, y = (idx >> 5) & 31, z = idx >> 10;
  float a = 0.f;
  for (int dz = 0; dz < 3; dz++)
    for (int dy = 0; dy < 3; dy++)
      for (int dx = 0; dx < 3; dx++) {
        const _Float16* p =
            P + (size_t)(((z + dz) * 34 + (y + dy)) * 34 + (x + dx)) * 32;
        const float* ww = &w[((dz * 3 + dy) * 3 + dx) * 32];
#pragma unroll
        for (int c = 0; c < 32; c += 8) {
          half8 pv = *(const half8*)&p[c];
#pragma unroll
          for (int u = 0; u < 8; u++) a += (float)pv[u] * ww[c + u];
        }
      }
  O[idx] = a;
}

extern "C" void kernel_launch(void* const* d_in, const int* in_sizes, int n_in,
                              void* d_out, int out_size, void* d_ws,
                              size_t ws_size, hipStream_t stream) {
  const float* x  = (const float*)d_in[0];
  const float* w1 = (const float*)d_in[1];
  const float* w2 = (const float*)d_in[2];
  const float* w3 = (const float*)d_in[3];
  const float* w4 = (const float*)d_in[4];
  const float* w5 = (const float*)d_in[5];
  const float* w6 = (const float*)d_in[6];
  float* out = (float*)d_out;

  // fp32 partial slabs
  float* Q1 = (float*)d_ws;                  // 108 * 64   * 512 = 3538944
  float* Q2 = Q1 + 3538944;                  // 24  * 512  * 256 = 3145728
  float* Q3 = Q2 + 3145728;                  // 54  * 512  * 128 = 3538944
  float* Q4 = Q3 + 3538944;                  // 12  * 4096 * 64  = 3145728
  // fp16 padded activations
  _Float16* P1 = (_Float16*)(Q4 + 3145728);  // 5^3  * 1024 = 128000
  _Float16* P2 = P1 + 128000;                // 10^3 * 512  = 512000
  _Float16* P3 = P2 + 512000;                // 9^3  * 256  = 186624
  _Float16* P4 = P3 + 186624;                // 18^3 * 128  = 746496
  _Float16* P5 = P4 + 746496;                // 17^3 * 64   = 314432
  _Float16* P6 = P5 + 314432;                // 34^3 * 32   = 1257728

  // L1: 1024->512, 4^3 -> 8^3, s2; 27 pairs x 8 n x 4 ci = 864 blocks, NIT=8
  pad_x_k<<<500, 256, 0, stream>>>(x, P1);
  conv_mfma_k<256, 1024, 512, 64, 4, 4, 5, 1, 0, 3>
      <<<dim3(27, 8, 4), 256, 0, stream>>>(P1, w1, Q1);
  red_k<8, 512, 1, 4, 10><<<500, 256, 0, stream>>>(Q1, P2);
  // L2: 512->256, 8^3, s1; 3 tap-groups x 8 ci -> 24 splits, 384 blocks
  conv_mfma_k<64, 512, 256, 64, 8, 8, 10, 0, 9, 3>
      <<<dim3(4, 4, 24), 256, 0, stream>>>(P2, w2, Q2);
  red_k<8, 256, 0, 24, 9><<<183, 256, 0, stream>>>(Q2, P3);
  // L3: 256->128, 8^3 -> 16^3, s2; 27 pairs x 4 m x 2 n x 2 ci = 432 blocks
  conv_mfma_k<128, 256, 128, 64, 8, 8, 9, 1, 0, 3>
      <<<dim3(108, 2, 2), 256, 0, stream>>>(P3, w3, Q3);
  red_k<16, 128, 1, 2, 18><<<729, 256, 0, stream>>>(Q3, P4);
  // L4: 128->64, 16^3, s1; 3 tap-groups x 4 ci -> 12 splits, 384 blocks
  conv_mfma_k<32, 128, 64, 64, 8, 16, 18, 0, 9, 3>
      <<<dim3(32, 1, 12), 256, 0, stream>>>(P4, w4, Q4);
  // red4 + P6 zero fused (308 red blocks + 615 zero blocks)
  red4z_k<<<923, 256, 0, stream>>>(Q4, P5, P6);
  // L5: 64->32, 16^3 -> 32^3, s2 class-loop, fp16 ReLU store into padded P6
  conv_mfma_k<64, 64, 32, 32, 8, 16, 17, 2, 0, 2>
      <<<dim3(256, 1, 1), 256, 0, stream>>>(P5, w5, P6);
  // L6: 32->1, 32^3, s1, no final ReLU
  conv6_k<<<256, 128, 0, stream>>>(P6, w6, out);

  (void)in_sizes; (void)n_in; (void)out_size; (void)ws_size;
}